// Round 5
// baseline (132.265 us; speedup 1.0000x reference)
//
#include <hip/hip_runtime.h>
#include <math.h>

// Non-local attention: X [8, 64, 64, 64] fp32.
// Per batch b: Q=K=V = X_b^T  [S=4096, D=64];  out = softmax(Q K^T) V, stored [b][c][s].
//
// R5 = R4 with the combine-kernel grid fixed (was 4x OOB -> core dump).
//  - prepass3: Xbf bf16 [c][m] (unscaled, V source), XbfT bf16 [m][c] scaled by sqrt(log2 e)
//    (softmax = v_sub + v_exp only), scaled row norms + per-block max partials.
//  - attn_split<PARTIAL>: BM=64, 2 waves x 32 Q rows; split-K x2 (valid: fixed C-S max,
//    partials add). 40960 B LDS -> 4 blocks/CU.
//  - combine: out = (O0+O1)/(L0+L1), 2048 blocks (= out_size/4/256).

#define SEQ 4096
#define DIM 64
#define LDB 72
#define LDO 68
#define QSCALE 1.2011224087864498f   // sqrt(log2(e))

typedef __attribute__((ext_vector_type(8))) short  short8;
typedef __attribute__((ext_vector_type(4))) float  f32x4;

__device__ __forceinline__ unsigned short f2bf(float f) {
    union { float f; unsigned int u; } x; x.f = f;
    unsigned int u = x.u + 0x7FFFu + ((x.u >> 16) & 1u);
    return (unsigned short)(u >> 16);
}
__device__ __forceinline__ float bf2f(unsigned short h) {
    union { unsigned int u; float f; } x; x.u = ((unsigned int)h) << 16; return x.f;
}

#define LDT 68
__global__ __launch_bounds__(256) void prepass3(const float* __restrict__ X,
                                                unsigned short* __restrict__ Xbf,
                                                unsigned short* __restrict__ XbfT,
                                                float* __restrict__ Norms,
                                                float* __restrict__ MaxPart) {
    __shared__ __align__(16) unsigned short sT[64 * LDT];
    __shared__ float sRed[4];
    const int b = blockIdx.y, m0 = blockIdx.x * 64;
    const float* Xb = X + (size_t)b * DIM * SEQ;
    unsigned short* Bb = Xbf  + (size_t)b * DIM * SEQ;
    unsigned short* Tb = XbfT + (size_t)b * SEQ * DIM;
    const int t = threadIdx.x, w = t >> 6;
    const int mw = t & 15, cg = t >> 4;

    #pragma unroll
    for (int cr = 0; cr < 4; ++cr) {
        const int c = cg * 4 + cr;
        const f32x4 v = *(const f32x4*)(Xb + (size_t)c * SEQ + m0 + 4 * mw);
        *(ushort4*)(Bb + (size_t)c * SEQ + m0 + 4 * mw) =
            make_ushort4(f2bf(v.x), f2bf(v.y), f2bf(v.z), f2bf(v.w));
        sT[(4 * mw + 0) * LDT + c] = f2bf(v.x * QSCALE);
        sT[(4 * mw + 1) * LDT + c] = f2bf(v.y * QSCALE);
        sT[(4 * mw + 2) * LDT + c] = f2bf(v.z * QSCALE);
        sT[(4 * mw + 3) * LDT + c] = f2bf(v.w * QSCALE);
    }
    __syncthreads();
    const int m = t >> 2, ck = t & 3;
    const short8 a0 = *(const short8*)(sT + m * LDT + ck * 16);
    const short8 a1 = *(const short8*)(sT + m * LDT + ck * 16 + 8);
    *(short8*)(Tb + (size_t)(m0 + m) * DIM + ck * 16)     = a0;
    *(short8*)(Tb + (size_t)(m0 + m) * DIM + ck * 16 + 8) = a1;
    float s = 0.f;
    #pragma unroll
    for (int i = 0; i < 8; ++i) {
        const float f0 = bf2f((unsigned short)a0[i]);
        const float f1 = bf2f((unsigned short)a1[i]);
        s += f0 * f0 + f1 * f1;
    }
    s += __shfl_xor(s, 1);
    s += __shfl_xor(s, 2);
    const float nm = sqrtf(s);
    if (ck == 0) Norms[(size_t)b * SEQ + m0 + m] = nm;
    float mx = nm;
    #pragma unroll
    for (int d = 4; d < 64; d <<= 1) mx = fmaxf(mx, __shfl_xor(mx, d));
    if ((t & 63) == 0) sRed[w] = mx;
    __syncthreads();
    if (t == 0)
        MaxPart[b * 64 + blockIdx.x] =
            fmaxf(fmaxf(sRed[0], sRed[1]), fmaxf(sRed[2], sRed[3]));
}

template <bool PARTIAL>
__global__ __launch_bounds__(128, 2) void attn_split(const unsigned short* __restrict__ Xbf,
                                                     const unsigned short* __restrict__ XbfT,
                                                     const float* __restrict__ Norms,
                                                     const float* __restrict__ MaxPart,
                                                     float* __restrict__ Obase,
                                                     float* __restrict__ Lbase,
                                                     int niter) {
    __shared__ __align__(16) unsigned char smem[40960];
    unsigned short* sK = (unsigned short*)smem;
    unsigned short* sV = (unsigned short*)(smem + 16384);
    unsigned short* sP = (unsigned short*)(smem + 32768);
    float*          sO = (float*)smem;

    const int tid  = threadIdx.x;
    const int lane = tid & 63;
    const int w    = tid >> 6;
    const int l15  = lane & 15;
    const int quad = lane >> 4;

    const int b   = blockIdx.y;
    const int s0  = blockIdx.x * 64;
    const int h   = blockIdx.z;
    const int kt0 = h * niter;
    const unsigned short* Bb = Xbf  + (size_t)b * DIM * SEQ;
    const unsigned short* Tb = XbfT + (size_t)b * SEQ * DIM;
    float* Optr = Obase + (size_t)h * 8 * DIM * SEQ;
    float* Lptr = PARTIAL ? (Lbase + (size_t)h * 8 * SEQ) : nullptr;

    float mxn = MaxPart[b * 64 + lane];
    #pragma unroll
    for (int d = 1; d < 64; d <<= 1) mxn = fmaxf(mxn, __shfl_xor(mxn, d));

    short8 qf[2][2];
    float mrow[2];
    #pragma unroll
    for (int qt = 0; qt < 2; ++qt) {
        const int row = s0 + 32 * w + 16 * qt + l15;
        const unsigned short* qp = Tb + (size_t)row * DIM + quad * 8;
        qf[qt][0] = *(const short8*)(qp);
        qf[qt][1] = *(const short8*)(qp + 32);
        mrow[qt] = Norms[(size_t)b * SEQ + row] * mxn;
    }

    f32x4 acc_o[2][4];
    #pragma unroll
    for (int qt = 0; qt < 2; ++qt)
        #pragma unroll
        for (int ct = 0; ct < 4; ++ct) acc_o[qt][ct] = (f32x4){0.f, 0.f, 0.f, 0.f};
    float lp[2] = {0.f, 0.f};
    unsigned short* sPw = sP + w * 32 * 64;

    const int rl = lane >> 3, cgs = (lane & 7) ^ rl;
    int koff[4], voff[4], ldsoff[4];
    #pragma unroll
    for (int j = 0; j < 4; ++j) {
        const int row_j = w * 8 + j * 16 + rl;
        koff[j]   = row_j * 64 + cgs * 8;
        voff[j]   = row_j * 4096 + cgs * 8;
        ldsoff[j] = (w * 8 + j * 16) * 64;
    }
    auto stage = [&](int kt, int half) {
        unsigned short* sKb = sK + half * 4096;
        unsigned short* sVb = sV + half * 4096;
        #pragma unroll
        for (int j = 0; j < 4; ++j) {
            const unsigned short* gK = Tb + (size_t)kt * 4096 + koff[j];
            const unsigned short* gV = Bb + (size_t)kt * 64 + voff[j];
            __builtin_amdgcn_global_load_lds(
                (const __attribute__((address_space(1))) unsigned int*)gK,
                (__attribute__((address_space(3))) unsigned int*)(sKb + ldsoff[j]), 16, 0, 0);
            __builtin_amdgcn_global_load_lds(
                (const __attribute__((address_space(1))) unsigned int*)gV,
                (__attribute__((address_space(3))) unsigned int*)(sVb + ldsoff[j]), 16, 0, 0);
        }
    };

    const int rsw = l15 & 7;
    auto compute = [&](int half) {
        const unsigned short* sKc = sK + half * 4096;
        const unsigned short* sVc = sV + half * 4096;
        short8 kf[2][4], vf[2][4];
        #pragma unroll
        for (int t4 = 0; t4 < 4; ++t4) {
            const int rowoff = (16 * t4 + l15) << 6;
            #pragma unroll
            for (int ks = 0; ks < 2; ++ks) {
                const int cgr = (((quad + 4 * ks) ^ rsw) << 3);
                kf[ks][t4] = *(const short8*)(sKc + rowoff + cgr);
                vf[ks][t4] = *(const short8*)(sVc + rowoff + cgr);
            }
        }
        #pragma unroll
        for (int qt = 0; qt < 2; ++qt) {
            const int nloc = 16 * qt + l15;
            #pragma unroll
            for (int mt = 0; mt < 4; ++mt) {
                f32x4 a = (f32x4){0.f, 0.f, 0.f, 0.f};
                a = __builtin_amdgcn_mfma_f32_16x16x32_bf16(kf[0][mt], qf[qt][0], a, 0, 0, 0);
                a = __builtin_amdgcn_mfma_f32_16x16x32_bf16(kf[1][mt], qf[qt][1], a, 0, 0, 0);
                const float p0 = exp2f(a[0] - mrow[qt]);
                const float p1 = exp2f(a[1] - mrow[qt]);
                const float p2 = exp2f(a[2] - mrow[qt]);
                const float p3 = exp2f(a[3] - mrow[qt]);
                lp[qt] += (p0 + p1) + (p2 + p3);
                const unsigned u0 = __float_as_uint(p0) + 0x8000u;
                const unsigned u1 = __float_as_uint(p1) + 0x8000u;
                const unsigned u2 = __float_as_uint(p2) + 0x8000u;
                const unsigned u3 = __float_as_uint(p3) + 0x8000u;
                const unsigned lo = __builtin_amdgcn_perm(u1, u0, 0x07060302u);
                const unsigned hi = __builtin_amdgcn_perm(u3, u2, 0x07060302u);
                const int chk = (2 * mt + (quad >> 1)) ^ rsw;
                *(uint2*)(sPw + nloc * 64 + chk * 8 + 4 * (quad & 1)) = make_uint2(lo, hi);
            }
            const short8 pf0 = *(const short8*)(sPw + nloc * 64 + ((quad)     ^ rsw) * 8);
            const short8 pf1 = *(const short8*)(sPw + nloc * 64 + ((quad + 4) ^ rsw) * 8);
            #pragma unroll
            for (int ct = 0; ct < 4; ++ct) {
                acc_o[qt][ct] = __builtin_amdgcn_mfma_f32_16x16x32_bf16(pf0, vf[0][ct], acc_o[qt][ct], 0, 0, 0);
                acc_o[qt][ct] = __builtin_amdgcn_mfma_f32_16x16x32_bf16(pf1, vf[1][ct], acc_o[qt][ct], 0, 0, 0);
            }
        }
    };

    stage(kt0, 0);
    __syncthreads();
    for (int it = 0; it < niter; it += 2) {
        if (it + 1 < niter) stage(kt0 + it + 1, 1);
        compute(0);
        __syncthreads();
        if (it + 2 < niter) stage(kt0 + it + 2, 0);
        compute(1);
        __syncthreads();
    }

    #pragma unroll
    for (int qt = 0; qt < 2; ++qt) {
        lp[qt] += __shfl_xor(lp[qt], 16);
        lp[qt] += __shfl_xor(lp[qt], 32);
    }

    if (PARTIAL) {
        if (quad == 0) {
            #pragma unroll
            for (int qt = 0; qt < 2; ++qt)
                Lptr[(size_t)b * SEQ + s0 + 32 * w + 16 * qt + l15] = lp[qt];
        }
    } else {
        #pragma unroll
        for (int qt = 0; qt < 2; ++qt) {
            float inv[4];
            #pragma unroll
            for (int r = 0; r < 4; ++r) inv[r] = 1.f / __shfl(lp[qt], 4 * quad + r);
            #pragma unroll
            for (int ct = 0; ct < 4; ++ct)
                #pragma unroll
                for (int r = 0; r < 4; ++r) acc_o[qt][ct][r] *= inv[r];
        }
    }

    #pragma unroll
    for (int qt = 0; qt < 2; ++qt)
        #pragma unroll
        for (int ct = 0; ct < 4; ++ct) {
            const int c = 16 * ct + l15;
            #pragma unroll
            for (int r = 0; r < 4; ++r)
                sO[c * LDO + 32 * w + 16 * qt + 4 * quad + r] = acc_o[qt][ct][r];
        }
    __syncthreads();
    const int mw = tid & 15, cg = tid >> 4;
    #pragma unroll
    for (int cc = 0; cc < 8; ++cc) {
        const int c = cg + 8 * cc;
        const f32x4 v = *(const f32x4*)(sO + c * LDO + 4 * mw);
        *(f32x4*)(Optr + ((size_t)b * DIM + c) * SEQ + s0 + 4 * mw) = v;
    }
}

__global__ __launch_bounds__(256) void combine_kernel(const float* __restrict__ O0,
                                                      const float* __restrict__ O1,
                                                      const float* __restrict__ L0,
                                                      const float* __restrict__ L1,
                                                      float* __restrict__ Out) {
    const int gid = blockIdx.x * 256 + threadIdx.x;
    const size_t base = (size_t)gid * 4;
    const int s = (int)(base & 4095);
    const int b = (int)(base >> 18);
    const f32x4 o0 = *(const f32x4*)(O0 + base);
    const f32x4 o1 = *(const f32x4*)(O1 + base);
    const f32x4 l0 = *(const f32x4*)(L0 + b * SEQ + s);
    const f32x4 l1 = *(const f32x4*)(L1 + b * SEQ + s);
    f32x4 o;
    #pragma unroll
    for (int i = 0; i < 4; ++i) o[i] = (o0[i] + o1[i]) / (l0[i] + l1[i]);
    *(f32x4*)(Out + base) = o;
}

__global__ __launch_bounds__(256, 2) void attn_fallback(const float* __restrict__ X,
                                                        float* __restrict__ Out) {
    __shared__ __align__(16) unsigned char smem[27648];
    unsigned short* sK = (unsigned short*)smem;
    unsigned short* sV = (unsigned short*)(smem + 9216);
    unsigned short* sP = (unsigned short*)(smem + 18432);
    float*          sO = (float*)smem;
    const int tid  = threadIdx.x;
    const int lane = tid & 63;
    const int w    = tid >> 6;
    const int l15  = lane & 15;
    const int quad = lane >> 4;
    const int b  = blockIdx.y;
    const int s0 = blockIdx.x * 64;
    const float* Xb = X + (size_t)b * DIM * SEQ;
    const int mgrp = tid & 15;
    const int c0   = tid >> 4;

    for (int cc = 0; cc < 4; ++cc) {
        int c = c0 + 16 * cc;
        const f32x4 v = *(const f32x4*)(Xb + (size_t)c * SEQ + s0 + 4 * mgrp);
        sK[(4 * mgrp + 0) * LDB + c] = f2bf(v.x);
        sK[(4 * mgrp + 1) * LDB + c] = f2bf(v.y);
        sK[(4 * mgrp + 2) * LDB + c] = f2bf(v.z);
        sK[(4 * mgrp + 3) * LDB + c] = f2bf(v.w);
    }
    __syncthreads();
    short8 qf0, qf1;
    {
        const int row = 16 * w + l15;
        qf0 = *(const short8*)(sK + row * LDB + quad * 8);
        qf1 = *(const short8*)(sK + row * LDB + 32 + quad * 8);
    }
    __syncthreads();
    f32x4 acc_o[4];
    for (int ct = 0; ct < 4; ++ct) acc_o[ct] = (f32x4){0.f, 0.f, 0.f, 0.f};
    float m_i[4] = {-1e30f, -1e30f, -1e30f, -1e30f};
    float l_i[4] = {0.f, 0.f, 0.f, 0.f};
    for (int kt = 0; kt < SEQ / 64; ++kt) {
        const int m0 = kt * 64;
        for (int cc = 0; cc < 4; ++cc) {
            int c = c0 + 16 * cc;
            const f32x4 v = *(const f32x4*)(Xb + (size_t)c * SEQ + m0 + 4 * mgrp);
            unsigned short h0 = f2bf(v.x), h1 = f2bf(v.y), h2 = f2bf(v.z), h3 = f2bf(v.w);
            *(ushort4*)(sV + c * LDB + 4 * mgrp) = make_ushort4(h0, h1, h2, h3);
            sK[(4 * mgrp + 0) * LDB + c] = h0;
            sK[(4 * mgrp + 1) * LDB + c] = h1;
            sK[(4 * mgrp + 2) * LDB + c] = h2;
            sK[(4 * mgrp + 3) * LDB + c] = h3;
        }
        __syncthreads();
        short8 vf[2][4];
        for (int ks = 0; ks < 2; ++ks)
            for (int ct = 0; ct < 4; ++ct)
                vf[ks][ct] = *(const short8*)(sV + (16 * ct + l15) * LDB + ks * 32 + quad * 8);
        f32x4 acc_s[4];
        for (int mt = 0; mt < 4; ++mt) {
            const int row = 16 * mt + l15;
            const short8 kf0 = *(const short8*)(sK + row * LDB + quad * 8);
            const short8 kf1 = *(const short8*)(sK + row * LDB + 32 + quad * 8);
            f32x4 a = (f32x4){0.f, 0.f, 0.f, 0.f};
            a = __builtin_amdgcn_mfma_f32_16x16x32_bf16(qf0, kf0, a, 0, 0, 0);
            a = __builtin_amdgcn_mfma_f32_16x16x32_bf16(qf1, kf1, a, 0, 0, 0);
            acc_s[mt] = a;
        }
        float alpha[4];
        for (int r = 0; r < 4; ++r) {
            float mx = fmaxf(fmaxf(acc_s[0][r], acc_s[1][r]), fmaxf(acc_s[2][r], acc_s[3][r]));
            mx = fmaxf(mx, __shfl_xor(mx, 1));
            mx = fmaxf(mx, __shfl_xor(mx, 2));
            mx = fmaxf(mx, __shfl_xor(mx, 4));
            mx = fmaxf(mx, __shfl_xor(mx, 8));
            const float mnew = fmaxf(m_i[r], mx);
            alpha[r] = __expf(m_i[r] - mnew);
            m_i[r] = mnew;
        }
        float rowsum[4] = {0.f, 0.f, 0.f, 0.f};
        unsigned short pb[4][4];
        for (int mt = 0; mt < 4; ++mt)
            for (int r = 0; r < 4; ++r) {
                const float p = __expf(acc_s[mt][r] - m_i[r]);
                rowsum[r] += p;
                pb[mt][r] = f2bf(p);
            }
        for (int r = 0; r < 4; ++r) {
            float s = rowsum[r];
            s += __shfl_xor(s, 1);
            s += __shfl_xor(s, 2);
            s += __shfl_xor(s, 4);
            s += __shfl_xor(s, 8);
            l_i[r] = alpha[r] * l_i[r] + s;
        }
        for (int ct = 0; ct < 4; ++ct)
            for (int r = 0; r < 4; ++r)
                acc_o[ct][r] *= alpha[r];
        for (int mt = 0; mt < 4; ++mt)
            for (int r = 0; r < 4; ++r)
                sP[(16 * w + quad * 4 + r) * LDB + l15 + 16 * mt] = pb[mt][r];
        __syncthreads();
        const short8 pf0 = *(const short8*)(sP + (16 * w + l15) * LDB + quad * 8);
        const short8 pf1 = *(const short8*)(sP + (16 * w + l15) * LDB + 32 + quad * 8);
        for (int ct = 0; ct < 4; ++ct) {
            acc_o[ct] = __builtin_amdgcn_mfma_f32_16x16x32_bf16(pf0, vf[0][ct], acc_o[ct], 0, 0, 0);
            acc_o[ct] = __builtin_amdgcn_mfma_f32_16x16x32_bf16(pf1, vf[1][ct], acc_o[ct], 0, 0, 0);
        }
    }
    float inv[4];
    for (int r = 0; r < 4; ++r) inv[r] = 1.f / l_i[r];
    for (int ct = 0; ct < 4; ++ct) {
        const int c = 16 * ct + l15;
        for (int r = 0; r < 4; ++r)
            sO[c * LDO + 16 * w + quad * 4 + r] = acc_o[ct][r] * inv[r];
    }
    __syncthreads();
    for (int cc = 0; cc < 4; ++cc) {
        const int c = c0 + 16 * cc;
        const f32x4 v = *(const f32x4*)(sO + c * LDO + 4 * mgrp);
        *(f32x4*)(Out + (size_t)b * DIM * SEQ + (size_t)c * SEQ + s0 + 4 * mgrp) = v;
    }
}

extern "C" void kernel_launch(void* const* d_in, const int* in_sizes, int n_in,
                              void* d_out, int out_size, void* d_ws, size_t ws_size,
                              hipStream_t stream) {
    const float* X = (const float*)d_in[0];
    float* Out = (float*)d_out;
    const size_t elems = (size_t)8 * SEQ * DIM;
    const size_t offXbfT  = elems * 2;
    const size_t offNorms = offXbfT + elems * 2;
    const size_t offMaxP  = offNorms + (size_t)8 * SEQ * 4;
    const size_t offOpart = offMaxP + 8 * 64 * 4;
    const size_t offLpart = offOpart + 2 * elems * 4;
    const size_t need_split = offLpart + 2 * (size_t)8 * SEQ * 4;
    const size_t need_h1    = offOpart;

    if (ws_size >= need_h1) {
        unsigned short* Xbf   = (unsigned short*)d_ws;
        unsigned short* XbfT  = (unsigned short*)((char*)d_ws + offXbfT);
        float* Norms   = (float*)((char*)d_ws + offNorms);
        float* MaxPart = (float*)((char*)d_ws + offMaxP);
        prepass3<<<dim3(64, 8), 256, 0, stream>>>(X, Xbf, XbfT, Norms, MaxPart);
        if (ws_size >= need_split) {
            float* O0 = (float*)((char*)d_ws + offOpart);
            float* O1 = O0 + elems;
            float* L0 = (float*)((char*)d_ws + offLpart);
            float* L1 = L0 + (size_t)8 * SEQ;
            attn_split<true><<<dim3(64, 8, 2), 128, 0, stream>>>(Xbf, XbfT, Norms, MaxPart,
                                                                 O0, L0, 32);
            const int ngrp = (int)(elems / 4 / 256);   // 2048 blocks: exactly out_size elements
            combine_kernel<<<ngrp, 256, 0, stream>>>(O0, O1, L0, L1, Out);
        } else {
            attn_split<false><<<dim3(64, 8, 1), 128, 0, stream>>>(Xbf, XbfT, Norms, MaxPart,
                                                                  Out, nullptr, 64);
        }
    } else {
        attn_fallback<<<dim3(64, 8), 256, 0, stream>>>(X, Out);
    }
}

// Round 6
// 131.299 us; speedup vs baseline: 1.0074x; 1.0074x over previous
//
#include <hip/hip_runtime.h>
#include <math.h>
#include <type_traits>

// Non-local attention: X [8, 64, 64, 64] fp32.
// Per batch b: Q=K=V = X_b^T  [S=4096, D=64];  out = softmax(Q K^T) V, stored [b][c][s].
//
// R6 = R5 structure with VALU surgery:
//  - double-buffer halves unrolled at compile time -> LDS addrs = 1 VGPR base + imm offset
//  - staging global addrs = pointer registers incremented by constants
//  - softmax bound folded into MFMA C-init (no per-score subtract)

#define SEQ 4096
#define DIM 64
#define LDB 72
#define LDO 68
#define QSCALE 1.2011224087864498f   // sqrt(log2(e))

typedef __attribute__((ext_vector_type(8))) short  short8;
typedef __attribute__((ext_vector_type(4))) float  f32x4;

__device__ __forceinline__ unsigned short f2bf(float f) {
    union { float f; unsigned int u; } x; x.f = f;
    unsigned int u = x.u + 0x7FFFu + ((x.u >> 16) & 1u);
    return (unsigned short)(u >> 16);
}
__device__ __forceinline__ float bf2f(unsigned short h) {
    union { unsigned int u; float f; } x; x.u = ((unsigned int)h) << 16; return x.f;
}

#define LDT 68
__global__ __launch_bounds__(256) void prepass3(const float* __restrict__ X,
                                                unsigned short* __restrict__ Xbf,
                                                unsigned short* __restrict__ XbfT,
                                                float* __restrict__ Norms,
                                                float* __restrict__ MaxPart) {
    __shared__ __align__(16) unsigned short sT[64 * LDT];
    __shared__ float sRed[4];
    const int b = blockIdx.y, m0 = blockIdx.x * 64;
    const float* Xb = X + (size_t)b * DIM * SEQ;
    unsigned short* Bb = Xbf  + (size_t)b * DIM * SEQ;
    unsigned short* Tb = XbfT + (size_t)b * SEQ * DIM;
    const int t = threadIdx.x, w = t >> 6;
    const int mw = t & 15, cg = t >> 4;

    #pragma unroll
    for (int cr = 0; cr < 4; ++cr) {
        const int c = cg * 4 + cr;
        const f32x4 v = *(const f32x4*)(Xb + (size_t)c * SEQ + m0 + 4 * mw);
        *(ushort4*)(Bb + (size_t)c * SEQ + m0 + 4 * mw) =
            make_ushort4(f2bf(v.x), f2bf(v.y), f2bf(v.z), f2bf(v.w));
        sT[(4 * mw + 0) * LDT + c] = f2bf(v.x * QSCALE);
        sT[(4 * mw + 1) * LDT + c] = f2bf(v.y * QSCALE);
        sT[(4 * mw + 2) * LDT + c] = f2bf(v.z * QSCALE);
        sT[(4 * mw + 3) * LDT + c] = f2bf(v.w * QSCALE);
    }
    __syncthreads();
    const int m = t >> 2, ck = t & 3;
    const short8 a0 = *(const short8*)(sT + m * LDT + ck * 16);
    const short8 a1 = *(const short8*)(sT + m * LDT + ck * 16 + 8);
    *(short8*)(Tb + (size_t)(m0 + m) * DIM + ck * 16)     = a0;
    *(short8*)(Tb + (size_t)(m0 + m) * DIM + ck * 16 + 8) = a1;
    float s = 0.f;
    #pragma unroll
    for (int i = 0; i < 8; ++i) {
        const float f0 = bf2f((unsigned short)a0[i]);
        const float f1 = bf2f((unsigned short)a1[i]);
        s += f0 * f0 + f1 * f1;
    }
    s += __shfl_xor(s, 1);
    s += __shfl_xor(s, 2);
    const float nm = sqrtf(s);
    if (ck == 0) Norms[(size_t)b * SEQ + m0 + m] = nm;
    float mx = nm;
    #pragma unroll
    for (int d = 4; d < 64; d <<= 1) mx = fmaxf(mx, __shfl_xor(mx, d));
    if ((t & 63) == 0) sRed[w] = mx;
    __syncthreads();
    if (t == 0)
        MaxPart[b * 64 + blockIdx.x] =
            fmaxf(fmaxf(sRed[0], sRed[1]), fmaxf(sRed[2], sRed[3]));
}

template <bool PARTIAL>
__global__ __launch_bounds__(128, 2) void attn_split(const unsigned short* __restrict__ Xbf,
                                                     const unsigned short* __restrict__ XbfT,
                                                     const float* __restrict__ Norms,
                                                     const float* __restrict__ MaxPart,
                                                     float* __restrict__ Obase,
                                                     float* __restrict__ Lbase,
                                                     int niter) {
    __shared__ __align__(16) unsigned char smem[40960];
    unsigned short* sK = (unsigned short*)smem;            // 2 x 4096 shorts (dbuf)
    unsigned short* sV = (unsigned short*)(smem + 16384);  // 2 x 4096 shorts (dbuf)
    unsigned short* sP = (unsigned short*)(smem + 32768);  // 2 waves x 32 x 64 shorts
    float*          sO = (float*)smem;                     // epilogue overlay

    const int tid  = threadIdx.x;
    const int lane = tid & 63;
    const int w    = tid >> 6;
    const int l15  = lane & 15;
    const int quad = lane >> 4;

    const int b   = blockIdx.y;
    const int s0  = blockIdx.x * 64;
    const int h   = blockIdx.z;
    const int kt0 = h * niter;
    const unsigned short* Bb = Xbf  + (size_t)b * DIM * SEQ;
    const unsigned short* Tb = XbfT + (size_t)b * SEQ * DIM;
    float* Optr = Obase + (size_t)h * 8 * DIM * SEQ;
    float* Lptr = PARTIAL ? (Lbase + (size_t)h * 8 * SEQ) : nullptr;

    float mxn = MaxPart[b * 64 + lane];
    #pragma unroll
    for (int d = 1; d < 64; d <<= 1) mxn = fmaxf(mxn, __shfl_xor(mxn, d));

    short8 qf[2][2];
    f32x4 cin[2];                       // MFMA C-init = -mrow (fold softmax bound into matmul)
    #pragma unroll
    for (int qt = 0; qt < 2; ++qt) {
        const int row = s0 + 32 * w + 16 * qt + l15;
        const unsigned short* qp = Tb + (size_t)row * DIM + quad * 8;
        qf[qt][0] = *(const short8*)(qp);
        qf[qt][1] = *(const short8*)(qp + 32);
        const float mrow = Norms[(size_t)b * SEQ + row] * mxn;
        cin[qt] = (f32x4){-mrow, -mrow, -mrow, -mrow};
    }

    f32x4 acc_o[2][4];
    #pragma unroll
    for (int qt = 0; qt < 2; ++qt)
        #pragma unroll
        for (int ct = 0; ct < 4; ++ct) acc_o[qt][ct] = (f32x4){0.f, 0.f, 0.f, 0.f};
    float lp[2] = {0.f, 0.f};

    // ---- loop-invariant address precompute ----
    const int rsw = l15 & 7;
    const unsigned short* kb[2];   // frag read bases, ks = 0,1 (add imm: half*4096 + t4*1024 shorts)
    const unsigned short* vb[2];
    #pragma unroll
    for (int ks = 0; ks < 2; ++ks) {
        const int cgr = (((quad + 4 * ks) ^ rsw) << 3);
        kb[ks] = sK + (l15 << 6) + cgr;
        vb[ks] = sV + (l15 << 6) + cgr;
    }
    unsigned short* const sProw = sP + w * 32 * 64 + (l15 << 6);  // this wave, row l15 (qt imm +1024)
    unsigned short* pw[4];
    #pragma unroll
    for (int mt = 0; mt < 4; ++mt)
        pw[mt] = sProw + ((((2 * mt + (quad >> 1)) ^ rsw) << 3) + ((quad & 1) << 2));
    const unsigned short* pr[2];
    #pragma unroll
    for (int ks = 0; ks < 2; ++ks)
        pr[ks] = sProw + (((quad + 4 * ks) ^ rsw) << 3);

    // staging pointers (advance by constants; LDS dst is wave-uniform base + lane*16B)
    const int rl = lane >> 3, cgs = (lane & 7) ^ rl;
    const unsigned short* gK[4];
    const unsigned short* gV[4];
    #pragma unroll
    for (int j = 0; j < 4; ++j) {
        const int row_j = w * 8 + j * 16 + rl;
        gK[j] = Tb + (size_t)kt0 * 4096 + row_j * 64 + cgs * 8;
        gV[j] = Bb + (size_t)row_j * 4096 + (size_t)kt0 * 64 + cgs * 8;
    }
    auto stageTo = [&](auto HC) {
        constexpr int HALF = decltype(HC)::value;
        #pragma unroll
        for (int j = 0; j < 4; ++j) {
            __builtin_amdgcn_global_load_lds(
                (const __attribute__((address_space(1))) unsigned int*)gK[j],
                (__attribute__((address_space(3))) unsigned int*)(sK + HALF * 4096 + (w * 8 + j * 16) * 64),
                16, 0, 0);
            __builtin_amdgcn_global_load_lds(
                (const __attribute__((address_space(1))) unsigned int*)gV[j],
                (__attribute__((address_space(3))) unsigned int*)(sV + HALF * 4096 + (w * 8 + j * 16) * 64),
                16, 0, 0);
        }
        #pragma unroll
        for (int j = 0; j < 4; ++j) { gK[j] += 4096; gV[j] += 64; }
    };

    auto computeT = [&](auto HC) {
        constexpr int HALF = decltype(HC)::value;
        short8 kf[2][4], vf[2][4];
        #pragma unroll
        for (int t4 = 0; t4 < 4; ++t4)
            #pragma unroll
            for (int ks = 0; ks < 2; ++ks) {
                kf[ks][t4] = *(const short8*)(kb[ks] + HALF * 4096 + t4 * 1024);
                vf[ks][t4] = *(const short8*)(vb[ks] + HALF * 4096 + t4 * 1024);
            }
        #pragma unroll
        for (int qt = 0; qt < 2; ++qt) {
            #pragma unroll
            for (int mt = 0; mt < 4; ++mt) {
                f32x4 a = cin[qt];
                a = __builtin_amdgcn_mfma_f32_16x16x32_bf16(kf[0][mt], qf[qt][0], a, 0, 0, 0);
                a = __builtin_amdgcn_mfma_f32_16x16x32_bf16(kf[1][mt], qf[qt][1], a, 0, 0, 0);
                const float p0 = exp2f(a[0]);
                const float p1 = exp2f(a[1]);
                const float p2 = exp2f(a[2]);
                const float p3 = exp2f(a[3]);
                lp[qt] += (p0 + p1) + (p2 + p3);
                const unsigned u0 = __float_as_uint(p0) + 0x8000u;
                const unsigned u1 = __float_as_uint(p1) + 0x8000u;
                const unsigned u2 = __float_as_uint(p2) + 0x8000u;
                const unsigned u3 = __float_as_uint(p3) + 0x8000u;
                const unsigned lo = __builtin_amdgcn_perm(u1, u0, 0x07060302u);
                const unsigned hi = __builtin_amdgcn_perm(u3, u2, 0x07060302u);
                *(uint2*)(pw[mt] + qt * 1024) = make_uint2(lo, hi);
            }
            const short8 pf0 = *(const short8*)(pr[0] + qt * 1024);
            const short8 pf1 = *(const short8*)(pr[1] + qt * 1024);
            #pragma unroll
            for (int ct = 0; ct < 4; ++ct) {
                acc_o[qt][ct] = __builtin_amdgcn_mfma_f32_16x16x32_bf16(pf0, vf[0][ct], acc_o[qt][ct], 0, 0, 0);
                acc_o[qt][ct] = __builtin_amdgcn_mfma_f32_16x16x32_bf16(pf1, vf[1][ct], acc_o[qt][ct], 0, 0, 0);
            }
        }
    };

    std::integral_constant<int, 0> H0;
    std::integral_constant<int, 1> H1;

    stageTo(H0);
    __syncthreads();
    for (int it = 0; it < niter; it += 2) {
        if (it + 1 < niter) stageTo(H1);
        computeT(H0);
        __syncthreads();
        if (it + 2 < niter) stageTo(H0);
        computeT(H1);
        __syncthreads();
    }

    #pragma unroll
    for (int qt = 0; qt < 2; ++qt) {
        lp[qt] += __shfl_xor(lp[qt], 16);
        lp[qt] += __shfl_xor(lp[qt], 32);
    }

    if (PARTIAL) {
        if (quad == 0) {
            #pragma unroll
            for (int qt = 0; qt < 2; ++qt)
                Lptr[(size_t)b * SEQ + s0 + 32 * w + 16 * qt + l15] = lp[qt];
        }
    } else {
        #pragma unroll
        for (int qt = 0; qt < 2; ++qt) {
            float inv[4];
            #pragma unroll
            for (int r = 0; r < 4; ++r) inv[r] = 1.f / __shfl(lp[qt], 4 * quad + r);
            #pragma unroll
            for (int ct = 0; ct < 4; ++ct)
                #pragma unroll
                for (int r = 0; r < 4; ++r) acc_o[qt][ct][r] *= inv[r];
        }
    }

    #pragma unroll
    for (int qt = 0; qt < 2; ++qt)
        #pragma unroll
        for (int ct = 0; ct < 4; ++ct) {
            const int c = 16 * ct + l15;
            #pragma unroll
            for (int r = 0; r < 4; ++r)
                sO[c * LDO + 32 * w + 16 * qt + 4 * quad + r] = acc_o[qt][ct][r];
        }
    __syncthreads();
    const int mw = tid & 15, cg = tid >> 4;
    #pragma unroll
    for (int cc = 0; cc < 8; ++cc) {
        const int c = cg + 8 * cc;
        const f32x4 v = *(const f32x4*)(sO + c * LDO + 4 * mw);
        *(f32x4*)(Optr + ((size_t)b * DIM + c) * SEQ + s0 + 4 * mw) = v;
    }
}

__global__ __launch_bounds__(256) void combine_kernel(const float* __restrict__ O0,
                                                      const float* __restrict__ O1,
                                                      const float* __restrict__ L0,
                                                      const float* __restrict__ L1,
                                                      float* __restrict__ Out) {
    const int gid = blockIdx.x * 256 + threadIdx.x;
    const size_t base = (size_t)gid * 4;
    const int s = (int)(base & 4095);
    const int b = (int)(base >> 18);
    const f32x4 o0 = *(const f32x4*)(O0 + base);
    const f32x4 o1 = *(const f32x4*)(O1 + base);
    const f32x4 l0 = *(const f32x4*)(L0 + b * SEQ + s);
    const f32x4 l1 = *(const f32x4*)(L1 + b * SEQ + s);
    f32x4 o;
    #pragma unroll
    for (int i = 0; i < 4; ++i) o[i] = (o0[i] + o1[i]) / (l0[i] + l1[i]);
    *(f32x4*)(Out + base) = o;
}

__global__ __launch_bounds__(256, 2) void attn_fallback(const float* __restrict__ X,
                                                        float* __restrict__ Out) {
    __shared__ __align__(16) unsigned char smem[27648];
    unsigned short* sK = (unsigned short*)smem;
    unsigned short* sV = (unsigned short*)(smem + 9216);
    unsigned short* sP = (unsigned short*)(smem + 18432);
    float*          sO = (float*)smem;
    const int tid  = threadIdx.x;
    const int lane = tid & 63;
    const int w    = tid >> 6;
    const int l15  = lane & 15;
    const int quad = lane >> 4;
    const int b  = blockIdx.y;
    const int s0 = blockIdx.x * 64;
    const float* Xb = X + (size_t)b * DIM * SEQ;
    const int mgrp = tid & 15;
    const int c0   = tid >> 4;

    for (int cc = 0; cc < 4; ++cc) {
        int c = c0 + 16 * cc;
        const f32x4 v = *(const f32x4*)(Xb + (size_t)c * SEQ + s0 + 4 * mgrp);
        sK[(4 * mgrp + 0) * LDB + c] = f2bf(v.x);
        sK[(4 * mgrp + 1) * LDB + c] = f2bf(v.y);
        sK[(4 * mgrp + 2) * LDB + c] = f2bf(v.z);
        sK[(4 * mgrp + 3) * LDB + c] = f2bf(v.w);
    }
    __syncthreads();
    short8 qf0, qf1;
    {
        const int row = 16 * w + l15;
        qf0 = *(const short8*)(sK + row * LDB + quad * 8);
        qf1 = *(const short8*)(sK + row * LDB + 32 + quad * 8);
    }
    __syncthreads();
    f32x4 acc_o[4];
    for (int ct = 0; ct < 4; ++ct) acc_o[ct] = (f32x4){0.f, 0.f, 0.f, 0.f};
    float m_i[4] = {-1e30f, -1e30f, -1e30f, -1e30f};
    float l_i[4] = {0.f, 0.f, 0.f, 0.f};
    for (int kt = 0; kt < SEQ / 64; ++kt) {
        const int m0 = kt * 64;
        for (int cc = 0; cc < 4; ++cc) {
            int c = c0 + 16 * cc;
            const f32x4 v = *(const f32x4*)(Xb + (size_t)c * SEQ + m0 + 4 * mgrp);
            unsigned short h0 = f2bf(v.x), h1 = f2bf(v.y), h2 = f2bf(v.z), h3 = f2bf(v.w);
            *(ushort4*)(sV + c * LDB + 4 * mgrp) = make_ushort4(h0, h1, h2, h3);
            sK[(4 * mgrp + 0) * LDB + c] = h0;
            sK[(4 * mgrp + 1) * LDB + c] = h1;
            sK[(4 * mgrp + 2) * LDB + c] = h2;
            sK[(4 * mgrp + 3) * LDB + c] = h3;
        }
        __syncthreads();
        short8 vf[2][4];
        for (int ks = 0; ks < 2; ++ks)
            for (int ct = 0; ct < 4; ++ct)
                vf[ks][ct] = *(const short8*)(sV + (16 * ct + l15) * LDB + ks * 32 + quad * 8);
        f32x4 acc_s[4];
        for (int mt = 0; mt < 4; ++mt) {
            const int row = 16 * mt + l15;
            const short8 kf0 = *(const short8*)(sK + row * LDB + quad * 8);
            const short8 kf1 = *(const short8*)(sK + row * LDB + 32 + quad * 8);
            f32x4 a = (f32x4){0.f, 0.f, 0.f, 0.f};
            a = __builtin_amdgcn_mfma_f32_16x16x32_bf16(qf0, kf0, a, 0, 0, 0);
            a = __builtin_amdgcn_mfma_f32_16x16x32_bf16(qf1, kf1, a, 0, 0, 0);
            acc_s[mt] = a;
        }
        float alpha[4];
        for (int r = 0; r < 4; ++r) {
            float mx = fmaxf(fmaxf(acc_s[0][r], acc_s[1][r]), fmaxf(acc_s[2][r], acc_s[3][r]));
            mx = fmaxf(mx, __shfl_xor(mx, 1));
            mx = fmaxf(mx, __shfl_xor(mx, 2));
            mx = fmaxf(mx, __shfl_xor(mx, 4));
            mx = fmaxf(mx, __shfl_xor(mx, 8));
            const float mnew = fmaxf(m_i[r], mx);
            alpha[r] = __expf(m_i[r] - mnew);
            m_i[r] = mnew;
        }
        float rowsum[4] = {0.f, 0.f, 0.f, 0.f};
        unsigned short pb[4][4];
        for (int mt = 0; mt < 4; ++mt)
            for (int r = 0; r < 4; ++r) {
                const float p = __expf(acc_s[mt][r] - m_i[r]);
                rowsum[r] += p;
                pb[mt][r] = f2bf(p);
            }
        for (int r = 0; r < 4; ++r) {
            float s = rowsum[r];
            s += __shfl_xor(s, 1);
            s += __shfl_xor(s, 2);
            s += __shfl_xor(s, 4);
            s += __shfl_xor(s, 8);
            l_i[r] = alpha[r] * l_i[r] + s;
        }
        for (int ct = 0; ct < 4; ++ct)
            for (int r = 0; r < 4; ++r)
                acc_o[ct][r] *= alpha[r];
        for (int mt = 0; mt < 4; ++mt)
            for (int r = 0; r < 4; ++r)
                sP[(16 * w + quad * 4 + r) * LDB + l15 + 16 * mt] = pb[mt][r];
        __syncthreads();
        const short8 pf0 = *(const short8*)(sP + (16 * w + l15) * LDB + quad * 8);
        const short8 pf1 = *(const short8*)(sP + (16 * w + l15) * LDB + 32 + quad * 8);
        for (int ct = 0; ct < 4; ++ct) {
            acc_o[ct] = __builtin_amdgcn_mfma_f32_16x16x32_bf16(pf0, vf[0][ct], acc_o[ct], 0, 0, 0);
            acc_o[ct] = __builtin_amdgcn_mfma_f32_16x16x32_bf16(pf1, vf[1][ct], acc_o[ct], 0, 0, 0);
        }
    }
    float inv[4];
    for (int r = 0; r < 4; ++r) inv[r] = 1.f / l_i[r];
    for (int ct = 0; ct < 4; ++ct) {
        const int c = 16 * ct + l15;
        for (int r = 0; r < 4; ++r)
            sO[c * LDO + 16 * w + quad * 4 + r] = acc_o[ct][r] * inv[r];
    }
    __syncthreads();
    for (int cc = 0; cc < 4; ++cc) {
        const int c = c0 + 16 * cc;
        const f32x4 v = *(const f32x4*)(sO + c * LDO + 4 * mgrp);
        *(f32x4*)(Out + (size_t)b * DIM * SEQ + (size_t)c * SEQ + s0 + 4 * mgrp) = v;
    }
}

extern "C" void kernel_launch(void* const* d_in, const int* in_sizes, int n_in,
                              void* d_out, int out_size, void* d_ws, size_t ws_size,
                              hipStream_t stream) {
    const float* X = (const float*)d_in[0];
    float* Out = (float*)d_out;
    const size_t elems = (size_t)8 * SEQ * DIM;
    const size_t offXbfT  = elems * 2;
    const size_t offNorms = offXbfT + elems * 2;
    const size_t offMaxP  = offNorms + (size_t)8 * SEQ * 4;
    const size_t offOpart = offMaxP + 8 * 64 * 4;
    const size_t offLpart = offOpart + 2 * elems * 4;
    const size_t need_split = offLpart + 2 * (size_t)8 * SEQ * 4;
    const size_t need_h1    = offOpart;

    if (ws_size >= need_h1) {
        unsigned short* Xbf   = (unsigned short*)d_ws;
        unsigned short* XbfT  = (unsigned short*)((char*)d_ws + offXbfT);
        float* Norms   = (float*)((char*)d_ws + offNorms);
        float* MaxPart = (float*)((char*)d_ws + offMaxP);
        prepass3<<<dim3(64, 8), 256, 0, stream>>>(X, Xbf, XbfT, Norms, MaxPart);
        if (ws_size >= need_split) {
            float* O0 = (float*)((char*)d_ws + offOpart);
            float* O1 = O0 + elems;
            float* L0 = (float*)((char*)d_ws + offLpart);
            float* L1 = L0 + (size_t)8 * SEQ;
            attn_split<true><<<dim3(64, 8, 2), 128, 0, stream>>>(Xbf, XbfT, Norms, MaxPart,
                                                                 O0, L0, 32);
            const int ngrp = (int)(elems / 4 / 256);   // 2048 blocks = exactly out_size
            combine_kernel<<<ngrp, 256, 0, stream>>>(O0, O1, L0, L1, Out);
        } else {
            attn_split<false><<<dim3(64, 8, 1), 128, 0, stream>>>(Xbf, XbfT, Norms, MaxPart,
                                                                  Out, nullptr, 64);
        }
    } else {
        attn_fallback<<<dim3(64, 8), 256, 0, stream>>>(X, Out);
    }
}

// Round 7
// 128.807 us; speedup vs baseline: 1.0268x; 1.0193x over previous
//
#include <hip/hip_runtime.h>
#include <math.h>
#include <type_traits>

// Non-local attention: X [8, 64, 64, 64] fp32.
// Per batch b: Q=K=V = X_b^T  [S=4096, D=64];  out = softmax(Q K^T) V, stored [b][c][s].
//
// R7: occupancy attack. R5/R6 were latency-bound at 8 waves/CU (no pipe >50%).
//  - BN=32 K-tiles -> LDS 20.5KB/block -> 8 blocks/CU capacity
//  - split-K x4 -> 2048 blocks -> 8 resident blocks/CU = 16 waves/CU (4/SIMD)
//  - partial O in bf16 (4 slabs fit the ws budget proven in R5)
//  - fixed Cauchy-Schwarz softmax bound folded into MFMA C-init; exp2-only softmax

#define SEQ 4096
#define DIM 64
#define LDB 72
#define LDO 68
#define QSCALE 1.2011224087864498f   // sqrt(log2(e))

typedef __attribute__((ext_vector_type(8))) short  short8;
typedef __attribute__((ext_vector_type(4))) float  f32x4;

__device__ __forceinline__ unsigned short f2bf(float f) {
    union { float f; unsigned int u; } x; x.f = f;
    unsigned int u = x.u + 0x7FFFu + ((x.u >> 16) & 1u);
    return (unsigned short)(u >> 16);
}
__device__ __forceinline__ float bf2f(unsigned short h) {
    union { unsigned int u; float f; } x; x.u = ((unsigned int)h) << 16; return x.f;
}

#define LDT 68
__global__ __launch_bounds__(256) void prepass3(const float* __restrict__ X,
                                                unsigned short* __restrict__ Xbf,
                                                unsigned short* __restrict__ XbfT,
                                                float* __restrict__ Norms,
                                                float* __restrict__ MaxPart) {
    __shared__ __align__(16) unsigned short sT[64 * LDT];
    __shared__ float sRed[4];
    const int b = blockIdx.y, m0 = blockIdx.x * 64;
    const float* Xb = X + (size_t)b * DIM * SEQ;
    unsigned short* Bb = Xbf  + (size_t)b * DIM * SEQ;
    unsigned short* Tb = XbfT + (size_t)b * SEQ * DIM;
    const int t = threadIdx.x, w = t >> 6;
    const int mw = t & 15, cg = t >> 4;

    #pragma unroll
    for (int cr = 0; cr < 4; ++cr) {
        const int c = cg * 4 + cr;
        const f32x4 v = *(const f32x4*)(Xb + (size_t)c * SEQ + m0 + 4 * mw);
        *(ushort4*)(Bb + (size_t)c * SEQ + m0 + 4 * mw) =
            make_ushort4(f2bf(v.x), f2bf(v.y), f2bf(v.z), f2bf(v.w));
        sT[(4 * mw + 0) * LDT + c] = f2bf(v.x * QSCALE);
        sT[(4 * mw + 1) * LDT + c] = f2bf(v.y * QSCALE);
        sT[(4 * mw + 2) * LDT + c] = f2bf(v.z * QSCALE);
        sT[(4 * mw + 3) * LDT + c] = f2bf(v.w * QSCALE);
    }
    __syncthreads();
    const int m = t >> 2, ck = t & 3;
    const short8 a0 = *(const short8*)(sT + m * LDT + ck * 16);
    const short8 a1 = *(const short8*)(sT + m * LDT + ck * 16 + 8);
    *(short8*)(Tb + (size_t)(m0 + m) * DIM + ck * 16)     = a0;
    *(short8*)(Tb + (size_t)(m0 + m) * DIM + ck * 16 + 8) = a1;
    float s = 0.f;
    #pragma unroll
    for (int i = 0; i < 8; ++i) {
        const float f0 = bf2f((unsigned short)a0[i]);
        const float f1 = bf2f((unsigned short)a1[i]);
        s += f0 * f0 + f1 * f1;
    }
    s += __shfl_xor(s, 1);
    s += __shfl_xor(s, 2);
    const float nm = sqrtf(s);
    if (ck == 0) Norms[(size_t)b * SEQ + m0 + m] = nm;
    float mx = nm;
    #pragma unroll
    for (int d = 4; d < 64; d <<= 1) mx = fmaxf(mx, __shfl_xor(mx, d));
    if ((t & 63) == 0) sRed[w] = mx;
    __syncthreads();
    if (t == 0)
        MaxPart[b * 64 + blockIdx.x] =
            fmaxf(fmaxf(sRed[0], sRed[1]), fmaxf(sRed[2], sRed[3]));
}

// BN=32 flash kernel, 2 waves x 32 Q rows, split-K x NSPLIT.
// LDS: sK dbuf 2x2048 shorts (8KB) | sV dbuf 2x2048 (8KB) | sP 2x1024 (4KB) = 20480B.
template <bool PARTIAL>
__global__ __launch_bounds__(128, 4) void attn_split4(const unsigned short* __restrict__ Xbf,
                                                      const unsigned short* __restrict__ XbfT,
                                                      const float* __restrict__ Norms,
                                                      const float* __restrict__ MaxPart,
                                                      unsigned short* __restrict__ Obf,  // PARTIAL
                                                      float* __restrict__ Lbase,         // PARTIAL
                                                      float* __restrict__ Out,           // !PARTIAL
                                                      int niter) {
    __shared__ __align__(16) unsigned char smem[20480];
    unsigned short* sK = (unsigned short*)smem;            // [half][row m 0..31][64]
    unsigned short* sV = (unsigned short*)(smem + 8192);   // [half][row c 0..63][32]
    unsigned short* sP = (unsigned short*)(smem + 16384);  // [wave][row n 0..31][32]
    float*          sO = (float*)smem;                     // epilogue overlay (17408B)

    const int tid  = threadIdx.x;
    const int lane = tid & 63;
    const int w    = tid >> 6;
    const int l15  = lane & 15;
    const int quad = lane >> 4;

    const int b   = blockIdx.y;
    const int s0  = blockIdx.x * 64;
    const int h   = blockIdx.z;
    const int kt0 = h * niter;
    const unsigned short* Bb = Xbf  + (size_t)b * DIM * SEQ;
    const unsigned short* Tb = XbfT + (size_t)b * SEQ * DIM;

    float mxn = MaxPart[b * 64 + lane];
    #pragma unroll
    for (int d = 1; d < 64; d <<= 1) mxn = fmaxf(mxn, __shfl_xor(mxn, d));

    short8 qf[2][2];
    f32x4 cin[2];
    #pragma unroll
    for (int qt = 0; qt < 2; ++qt) {
        const int row = s0 + 32 * w + 16 * qt + l15;
        const unsigned short* qp = Tb + (size_t)row * DIM + quad * 8;
        qf[qt][0] = *(const short8*)(qp);
        qf[qt][1] = *(const short8*)(qp + 32);
        const float mrow = Norms[(size_t)b * SEQ + row] * mxn;
        cin[qt] = (f32x4){-mrow, -mrow, -mrow, -mrow};
    }

    f32x4 acc_o[2][4];
    #pragma unroll
    for (int qt = 0; qt < 2; ++qt)
        #pragma unroll
        for (int ct = 0; ct < 4; ++ct) acc_o[qt][ct] = (f32x4){0.f, 0.f, 0.f, 0.f};
    float lp[2] = {0.f, 0.f};

    // ---- loop-invariant addresses ----
    const int rsw  = l15 & 7;                       // K 3-bit key (128B rows)
    const int vkey = (l15 & 3) ^ (l15 >> 2);        // V/P 2-bit key (64B rows)
    const unsigned short* kb[2];
    #pragma unroll
    for (int ks = 0; ks < 2; ++ks)
        kb[ks] = sK + (l15 << 6) + (((quad + 4 * ks) ^ rsw) << 3);   // +HALF*2048 +mt*1024
    const unsigned short* vb = sV + (l15 << 5) + ((quad ^ vkey) << 3);  // +HALF*2048 +ct*512
    unsigned short* const prow = sP + (w << 10) + (l15 << 5);           // +qt*512
    unsigned short* pw[2];
    #pragma unroll
    for (int mt = 0; mt < 2; ++mt)
        pw[mt] = prow + ((((2 * mt + (quad >> 1)) ^ vkey) << 3) + ((quad & 1) << 2));
    const unsigned short* pr = prow + ((quad ^ vkey) << 3);

    // ---- staging (async global->LDS, 16B/lane) ----
    const int rl8 = lane >> 3, c8 = lane & 7;        // K: 8 rows x 8 chunks per call
    const int cgsK = c8 ^ rl8;
    const int rv = lane >> 2, cv = lane & 3;         // V: 16 rows x 4 chunks per call
    const int cvs = cv ^ ((rv & 3) ^ ((rv >> 2) & 3));
    const unsigned short* gK[2];
    const unsigned short* gV[2];
    #pragma unroll
    for (int j = 0; j < 2; ++j) {
        const int rowK = w * 16 + j * 8 + rl8;
        const int rowV = w * 32 + j * 16 + rv;
        gK[j] = Tb + (size_t)(kt0 * 32 + rowK) * 64 + cgsK * 8;
        gV[j] = Bb + (size_t)rowV * 4096 + kt0 * 32 + cvs * 8;
    }
    auto stageTo = [&](auto HC) {
        constexpr int HALF = decltype(HC)::value;
        #pragma unroll
        for (int j = 0; j < 2; ++j) {
            __builtin_amdgcn_global_load_lds(
                (const __attribute__((address_space(1))) unsigned int*)gK[j],
                (__attribute__((address_space(3))) unsigned int*)(sK + HALF * 2048 + (w * 16 + j * 8) * 64),
                16, 0, 0);
            __builtin_amdgcn_global_load_lds(
                (const __attribute__((address_space(1))) unsigned int*)gV[j],
                (__attribute__((address_space(3))) unsigned int*)(sV + HALF * 2048 + (w * 32 + j * 16) * 32),
                16, 0, 0);
        }
        #pragma unroll
        for (int j = 0; j < 2; ++j) { gK[j] += 2048; gV[j] += 32; }
    };

    auto computeT = [&](auto HC) {
        constexpr int HALF = decltype(HC)::value;
        short8 kf[2][2], vf[4];
        #pragma unroll
        for (int mt = 0; mt < 2; ++mt)
            #pragma unroll
            for (int ks = 0; ks < 2; ++ks)
                kf[ks][mt] = *(const short8*)(kb[ks] + HALF * 2048 + mt * 1024);
        #pragma unroll
        for (int ct = 0; ct < 4; ++ct)
            vf[ct] = *(const short8*)(vb + HALF * 2048 + ct * 512);
        #pragma unroll
        for (int qt = 0; qt < 2; ++qt) {
            #pragma unroll
            for (int mt = 0; mt < 2; ++mt) {
                f32x4 a = cin[qt];
                a = __builtin_amdgcn_mfma_f32_16x16x32_bf16(kf[0][mt], qf[qt][0], a, 0, 0, 0);
                a = __builtin_amdgcn_mfma_f32_16x16x32_bf16(kf[1][mt], qf[qt][1], a, 0, 0, 0);
                const float p0 = exp2f(a[0]);
                const float p1 = exp2f(a[1]);
                const float p2 = exp2f(a[2]);
                const float p3 = exp2f(a[3]);
                lp[qt] += (p0 + p1) + (p2 + p3);
                // truncating f32->bf16 pack (p in [0,1]; error << threshold)
                const unsigned lo = __builtin_amdgcn_perm(__float_as_uint(p1), __float_as_uint(p0), 0x07060302u);
                const unsigned hi = __builtin_amdgcn_perm(__float_as_uint(p3), __float_as_uint(p2), 0x07060302u);
                *(uint2*)(pw[mt] + qt * 512) = make_uint2(lo, hi);
            }
            const short8 pf = *(const short8*)(pr + qt * 512);
            #pragma unroll
            for (int ct = 0; ct < 4; ++ct)
                acc_o[qt][ct] = __builtin_amdgcn_mfma_f32_16x16x32_bf16(pf, vf[ct], acc_o[qt][ct], 0, 0, 0);
        }
    };

    std::integral_constant<int, 0> H0;
    std::integral_constant<int, 1> H1;

    stageTo(H0);
    __syncthreads();
    for (int it = 0; it < niter; it += 2) {
        if (it + 1 < niter) stageTo(H1);
        computeT(H0);
        __syncthreads();
        if (it + 2 < niter) stageTo(H0);
        computeT(H1);
        __syncthreads();
    }

    #pragma unroll
    for (int qt = 0; qt < 2; ++qt) {
        lp[qt] += __shfl_xor(lp[qt], 16);
        lp[qt] += __shfl_xor(lp[qt], 32);
    }

    if (PARTIAL) {
        if (quad == 0) {
            #pragma unroll
            for (int qt = 0; qt < 2; ++qt)
                (Lbase + (size_t)h * 8 * SEQ)[(size_t)b * SEQ + s0 + 32 * w + 16 * qt + l15] = lp[qt];
        }
    } else {
        #pragma unroll
        for (int qt = 0; qt < 2; ++qt) {
            float inv[4];
            #pragma unroll
            for (int r = 0; r < 4; ++r) inv[r] = 1.f / __shfl(lp[qt], 4 * quad + r);
            #pragma unroll
            for (int ct = 0; ct < 4; ++ct)
                #pragma unroll
                for (int r = 0; r < 4; ++r) acc_o[qt][ct][r] *= inv[r];
        }
    }

    #pragma unroll
    for (int qt = 0; qt < 2; ++qt)
        #pragma unroll
        for (int ct = 0; ct < 4; ++ct) {
            const int c = 16 * ct + l15;
            #pragma unroll
            for (int r = 0; r < 4; ++r)
                sO[c * LDO + 32 * w + 16 * qt + 4 * quad + r] = acc_o[qt][ct][r];
        }
    __syncthreads();
    const int mw = tid & 15, cg = tid >> 4;
    if (PARTIAL) {
        unsigned short* Op = Obf + (size_t)h * 8 * DIM * SEQ;
        #pragma unroll
        for (int cc = 0; cc < 8; ++cc) {
            const int c = cg + 8 * cc;
            const f32x4 v = *(const f32x4*)(sO + c * LDO + 4 * mw);
            *(ushort4*)(Op + ((size_t)b * DIM + c) * SEQ + s0 + 4 * mw) =
                make_ushort4(f2bf(v.x), f2bf(v.y), f2bf(v.z), f2bf(v.w));
        }
    } else {
        #pragma unroll
        for (int cc = 0; cc < 8; ++cc) {
            const int c = cg + 8 * cc;
            const f32x4 v = *(const f32x4*)(sO + c * LDO + 4 * mw);
            *(f32x4*)(Out + ((size_t)b * DIM + c) * SEQ + s0 + 4 * mw) = v;
        }
    }
}

__global__ __launch_bounds__(256) void combine4(const unsigned short* __restrict__ Obf,
                                                const float* __restrict__ Lp,
                                                float* __restrict__ Out) {
    const int gid = blockIdx.x * 256 + threadIdx.x;
    const size_t base = (size_t)gid * 4;
    const int s = (int)(base & 4095);
    const int b = (int)(base >> 18);
    f32x4 os = (f32x4){0.f, 0.f, 0.f, 0.f};
    f32x4 ls = (f32x4){0.f, 0.f, 0.f, 0.f};
    #pragma unroll
    for (int h = 0; h < 4; ++h) {
        const ushort4 o = *(const ushort4*)(Obf + (size_t)h * 2097152 + base);
        os[0] += bf2f(o.x); os[1] += bf2f(o.y); os[2] += bf2f(o.z); os[3] += bf2f(o.w);
        const f32x4 l = *(const f32x4*)(Lp + (size_t)h * 8 * SEQ + b * SEQ + s);
        #pragma unroll
        for (int i = 0; i < 4; ++i) ls[i] += l[i];
    }
    f32x4 o;
    #pragma unroll
    for (int i = 0; i < 4; ++i) o[i] = os[i] / ls[i];
    *(f32x4*)(Out + base) = o;
}

__global__ __launch_bounds__(256, 2) void attn_fallback(const float* __restrict__ X,
                                                        float* __restrict__ Out) {
    __shared__ __align__(16) unsigned char smem[27648];
    unsigned short* sK = (unsigned short*)smem;
    unsigned short* sV = (unsigned short*)(smem + 9216);
    unsigned short* sP = (unsigned short*)(smem + 18432);
    float*          sO = (float*)smem;
    const int tid  = threadIdx.x;
    const int lane = tid & 63;
    const int w    = tid >> 6;
    const int l15  = lane & 15;
    const int quad = lane >> 4;
    const int b  = blockIdx.y;
    const int s0 = blockIdx.x * 64;
    const float* Xb = X + (size_t)b * DIM * SEQ;
    const int mgrp = tid & 15;
    const int c0   = tid >> 4;

    for (int cc = 0; cc < 4; ++cc) {
        int c = c0 + 16 * cc;
        const f32x4 v = *(const f32x4*)(Xb + (size_t)c * SEQ + s0 + 4 * mgrp);
        sK[(4 * mgrp + 0) * LDB + c] = f2bf(v.x);
        sK[(4 * mgrp + 1) * LDB + c] = f2bf(v.y);
        sK[(4 * mgrp + 2) * LDB + c] = f2bf(v.z);
        sK[(4 * mgrp + 3) * LDB + c] = f2bf(v.w);
    }
    __syncthreads();
    short8 qf0, qf1;
    {
        const int row = 16 * w + l15;
        qf0 = *(const short8*)(sK + row * LDB + quad * 8);
        qf1 = *(const short8*)(sK + row * LDB + 32 + quad * 8);
    }
    __syncthreads();
    f32x4 acc_o[4];
    for (int ct = 0; ct < 4; ++ct) acc_o[ct] = (f32x4){0.f, 0.f, 0.f, 0.f};
    float m_i[4] = {-1e30f, -1e30f, -1e30f, -1e30f};
    float l_i[4] = {0.f, 0.f, 0.f, 0.f};
    for (int kt = 0; kt < SEQ / 64; ++kt) {
        const int m0 = kt * 64;
        for (int cc = 0; cc < 4; ++cc) {
            int c = c0 + 16 * cc;
            const f32x4 v = *(const f32x4*)(Xb + (size_t)c * SEQ + m0 + 4 * mgrp);
            unsigned short h0 = f2bf(v.x), h1 = f2bf(v.y), h2 = f2bf(v.z), h3 = f2bf(v.w);
            *(ushort4*)(sV + c * LDB + 4 * mgrp) = make_ushort4(h0, h1, h2, h3);
            sK[(4 * mgrp + 0) * LDB + c] = h0;
            sK[(4 * mgrp + 1) * LDB + c] = h1;
            sK[(4 * mgrp + 2) * LDB + c] = h2;
            sK[(4 * mgrp + 3) * LDB + c] = h3;
        }
        __syncthreads();
        short8 vf[2][4];
        for (int ks = 0; ks < 2; ++ks)
            for (int ct = 0; ct < 4; ++ct)
                vf[ks][ct] = *(const short8*)(sV + (16 * ct + l15) * LDB + ks * 32 + quad * 8);
        f32x4 acc_s[4];
        for (int mt = 0; mt < 4; ++mt) {
            const int row = 16 * mt + l15;
            const short8 kf0 = *(const short8*)(sK + row * LDB + quad * 8);
            const short8 kf1 = *(const short8*)(sK + row * LDB + 32 + quad * 8);
            f32x4 a = (f32x4){0.f, 0.f, 0.f, 0.f};
            a = __builtin_amdgcn_mfma_f32_16x16x32_bf16(qf0, kf0, a, 0, 0, 0);
            a = __builtin_amdgcn_mfma_f32_16x16x32_bf16(qf1, kf1, a, 0, 0, 0);
            acc_s[mt] = a;
        }
        float alpha[4];
        for (int r = 0; r < 4; ++r) {
            float mx = fmaxf(fmaxf(acc_s[0][r], acc_s[1][r]), fmaxf(acc_s[2][r], acc_s[3][r]));
            mx = fmaxf(mx, __shfl_xor(mx, 1));
            mx = fmaxf(mx, __shfl_xor(mx, 2));
            mx = fmaxf(mx, __shfl_xor(mx, 4));
            mx = fmaxf(mx, __shfl_xor(mx, 8));
            const float mnew = fmaxf(m_i[r], mx);
            alpha[r] = __expf(m_i[r] - mnew);
            m_i[r] = mnew;
        }
        float rowsum[4] = {0.f, 0.f, 0.f, 0.f};
        unsigned short pb[4][4];
        for (int mt = 0; mt < 4; ++mt)
            for (int r = 0; r < 4; ++r) {
                const float p = __expf(acc_s[mt][r] - m_i[r]);
                rowsum[r] += p;
                pb[mt][r] = f2bf(p);
            }
        for (int r = 0; r < 4; ++r) {
            float s = rowsum[r];
            s += __shfl_xor(s, 1);
            s += __shfl_xor(s, 2);
            s += __shfl_xor(s, 4);
            s += __shfl_xor(s, 8);
            l_i[r] = alpha[r] * l_i[r] + s;
        }
        for (int ct = 0; ct < 4; ++ct)
            for (int r = 0; r < 4; ++r)
                acc_o[ct][r] *= alpha[r];
        for (int mt = 0; mt < 4; ++mt)
            for (int r = 0; r < 4; ++r)
                sP[(16 * w + quad * 4 + r) * LDB + l15 + 16 * mt] = pb[mt][r];
        __syncthreads();
        const short8 pf0 = *(const short8*)(sP + (16 * w + l15) * LDB + quad * 8);
        const short8 pf1 = *(const short8*)(sP + (16 * w + l15) * LDB + 32 + quad * 8);
        for (int ct = 0; ct < 4; ++ct) {
            acc_o[ct] = __builtin_amdgcn_mfma_f32_16x16x32_bf16(pf0, vf[0][ct], acc_o[ct], 0, 0, 0);
            acc_o[ct] = __builtin_amdgcn_mfma_f32_16x16x32_bf16(pf1, vf[1][ct], acc_o[ct], 0, 0, 0);
        }
    }
    float inv[4];
    for (int r = 0; r < 4; ++r) inv[r] = 1.f / l_i[r];
    for (int ct = 0; ct < 4; ++ct) {
        const int c = 16 * ct + l15;
        for (int r = 0; r < 4; ++r)
            sO[c * LDO + 16 * w + quad * 4 + r] = acc_o[ct][r] * inv[r];
    }
    __syncthreads();
    for (int cc = 0; cc < 4; ++cc) {
        const int c = c0 + 16 * cc;
        const f32x4 v = *(const f32x4*)(sO + c * LDO + 4 * mgrp);
        *(f32x4*)(Out + (size_t)b * DIM * SEQ + (size_t)c * SEQ + s0 + 4 * mgrp) = v;
    }
}

extern "C" void kernel_launch(void* const* d_in, const int* in_sizes, int n_in,
                              void* d_out, int out_size, void* d_ws, size_t ws_size,
                              hipStream_t stream) {
    const float* X = (const float*)d_in[0];
    float* Out = (float*)d_out;
    const size_t elems = (size_t)8 * SEQ * DIM;               // 2M
    const size_t offXbfT  = elems * 2;                        // Xbf 4MB
    const size_t offNorms = offXbfT + elems * 2;              // 8MB
    const size_t offMaxP  = offNorms + (size_t)8 * SEQ * 4;   // +128KB
    const size_t offObf   = offMaxP + 8 * 64 * 4;             // +2KB
    const size_t offLpart = offObf + 4 * elems * 2;           // +16MB (4 bf16 slabs)
    const size_t need_split = offLpart + 4 * (size_t)8 * SEQ * 4;  // +512KB  (~24.64MB)
    const size_t need_h1    = offObf;

    if (ws_size >= need_h1) {
        unsigned short* Xbf   = (unsigned short*)d_ws;
        unsigned short* XbfT  = (unsigned short*)((char*)d_ws + offXbfT);
        float* Norms   = (float*)((char*)d_ws + offNorms);
        float* MaxPart = (float*)((char*)d_ws + offMaxP);
        prepass3<<<dim3(64, 8), 256, 0, stream>>>(X, Xbf, XbfT, Norms, MaxPart);
        if (ws_size >= need_split) {
            unsigned short* Obf = (unsigned short*)((char*)d_ws + offObf);
            float* Lp = (float*)((char*)d_ws + offLpart);
            attn_split4<true><<<dim3(64, 8, 4), 128, 0, stream>>>(Xbf, XbfT, Norms, MaxPart,
                                                                  Obf, Lp, nullptr, 32);
            combine4<<<(int)(elems / 1024), 256, 0, stream>>>(Obf, Lp, Out);
        } else {
            attn_split4<false><<<dim3(64, 8, 1), 128, 0, stream>>>(Xbf, XbfT, Norms, MaxPart,
                                                                   nullptr, nullptr, Out, 128);
        }
    } else {
        attn_fallback<<<dim3(64, 8), 256, 0, stream>>>(X, Out);
    }
}

// Round 8
// 115.488 us; speedup vs baseline: 1.1453x; 1.1153x over previous
//
#include <hip/hip_runtime.h>
#include <math.h>
#include <type_traits>

// Non-local attention: X [8, 64, 64, 64] fp32.
// Per batch b: Q=K=V = X_b^T  [S=4096, D=64];  out = softmax(Q K^T) V, stored [b][c][s].
//
// R8 = R7 (BN=32, split-K x4, 8 blocks/CU) + VALU surgery:
//  - raw v_exp_f32 (no libm denormal fixup) for the softmax exp
//  - computeT phase-reordered: S-MFMAs | exps/packs | P-writes | P-reads | PV-MFMAs
//  - 4-way lp partial accumulators; rcp epilogue

#define SEQ 4096
#define DIM 64
#define LDB 72
#define LDO 68
#define QSCALE 1.2011224087864498f   // sqrt(log2(e))

typedef __attribute__((ext_vector_type(8))) short  short8;
typedef __attribute__((ext_vector_type(4))) float  f32x4;

__device__ __forceinline__ unsigned short f2bf(float f) {
    union { float f; unsigned int u; } x; x.f = f;
    unsigned int u = x.u + 0x7FFFu + ((x.u >> 16) & 1u);
    return (unsigned short)(u >> 16);
}
__device__ __forceinline__ float bf2f(unsigned short h) {
    union { unsigned int u; float f; } x; x.u = ((unsigned int)h) << 16; return x.f;
}
__device__ __forceinline__ float fast_exp2(float x) {
#if __has_builtin(__builtin_amdgcn_exp2f)
    return __builtin_amdgcn_exp2f(x);
#else
    float r;
    asm("v_exp_f32 %0, %1\n\ts_nop 0" : "=v"(r) : "v"(x));   // s_nop: trans-op hazard
    return r;
#endif
}
__device__ __forceinline__ float fast_rcp(float x) {
#if __has_builtin(__builtin_amdgcn_rcpf)
    return __builtin_amdgcn_rcpf(x);
#else
    return 1.f / x;
#endif
}

#define LDT 68
__global__ __launch_bounds__(256) void prepass3(const float* __restrict__ X,
                                                unsigned short* __restrict__ Xbf,
                                                unsigned short* __restrict__ XbfT,
                                                float* __restrict__ Norms,
                                                float* __restrict__ MaxPart) {
    __shared__ __align__(16) unsigned short sT[64 * LDT];
    __shared__ float sRed[4];
    const int b = blockIdx.y, m0 = blockIdx.x * 64;
    const float* Xb = X + (size_t)b * DIM * SEQ;
    unsigned short* Bb = Xbf  + (size_t)b * DIM * SEQ;
    unsigned short* Tb = XbfT + (size_t)b * SEQ * DIM;
    const int t = threadIdx.x, w = t >> 6;
    const int mw = t & 15, cg = t >> 4;

    #pragma unroll
    for (int cr = 0; cr < 4; ++cr) {
        const int c = cg * 4 + cr;
        const f32x4 v = *(const f32x4*)(Xb + (size_t)c * SEQ + m0 + 4 * mw);
        *(ushort4*)(Bb + (size_t)c * SEQ + m0 + 4 * mw) =
            make_ushort4(f2bf(v.x), f2bf(v.y), f2bf(v.z), f2bf(v.w));
        sT[(4 * mw + 0) * LDT + c] = f2bf(v.x * QSCALE);
        sT[(4 * mw + 1) * LDT + c] = f2bf(v.y * QSCALE);
        sT[(4 * mw + 2) * LDT + c] = f2bf(v.z * QSCALE);
        sT[(4 * mw + 3) * LDT + c] = f2bf(v.w * QSCALE);
    }
    __syncthreads();
    const int m = t >> 2, ck = t & 3;
    const short8 a0 = *(const short8*)(sT + m * LDT + ck * 16);
    const short8 a1 = *(const short8*)(sT + m * LDT + ck * 16 + 8);
    *(short8*)(Tb + (size_t)(m0 + m) * DIM + ck * 16)     = a0;
    *(short8*)(Tb + (size_t)(m0 + m) * DIM + ck * 16 + 8) = a1;
    float s = 0.f;
    #pragma unroll
    for (int i = 0; i < 8; ++i) {
        const float f0 = bf2f((unsigned short)a0[i]);
        const float f1 = bf2f((unsigned short)a1[i]);
        s += f0 * f0 + f1 * f1;
    }
    s += __shfl_xor(s, 1);
    s += __shfl_xor(s, 2);
    const float nm = sqrtf(s);
    if (ck == 0) Norms[(size_t)b * SEQ + m0 + m] = nm;
    float mx = nm;
    #pragma unroll
    for (int d = 4; d < 64; d <<= 1) mx = fmaxf(mx, __shfl_xor(mx, d));
    if ((t & 63) == 0) sRed[w] = mx;
    __syncthreads();
    if (t == 0)
        MaxPart[b * 64 + blockIdx.x] =
            fmaxf(fmaxf(sRed[0], sRed[1]), fmaxf(sRed[2], sRed[3]));
}

// BN=32 flash kernel, 2 waves x 32 Q rows, split-K x4.
// LDS: sK dbuf 2x2048 shorts (8KB) | sV dbuf 2x2048 (8KB) | sP 2x1024 (4KB) = 20480B.
template <bool PARTIAL>
__global__ __launch_bounds__(128, 4) void attn_split4(const unsigned short* __restrict__ Xbf,
                                                      const unsigned short* __restrict__ XbfT,
                                                      const float* __restrict__ Norms,
                                                      const float* __restrict__ MaxPart,
                                                      unsigned short* __restrict__ Obf,  // PARTIAL
                                                      float* __restrict__ Lbase,         // PARTIAL
                                                      float* __restrict__ Out,           // !PARTIAL
                                                      int niter) {
    __shared__ __align__(16) unsigned char smem[20480];
    unsigned short* sK = (unsigned short*)smem;            // [half][row m 0..31][64]
    unsigned short* sV = (unsigned short*)(smem + 8192);   // [half][row c 0..63][32]
    unsigned short* sP = (unsigned short*)(smem + 16384);  // [wave][row n 0..31][32]
    float*          sO = (float*)smem;                     // epilogue overlay (17408B)

    const int tid  = threadIdx.x;
    const int lane = tid & 63;
    const int w    = tid >> 6;
    const int l15  = lane & 15;
    const int quad = lane >> 4;

    const int b   = blockIdx.y;
    const int s0  = blockIdx.x * 64;
    const int h   = blockIdx.z;
    const int kt0 = h * niter;
    const unsigned short* Bb = Xbf  + (size_t)b * DIM * SEQ;
    const unsigned short* Tb = XbfT + (size_t)b * SEQ * DIM;

    float mxn = MaxPart[b * 64 + lane];
    #pragma unroll
    for (int d = 1; d < 64; d <<= 1) mxn = fmaxf(mxn, __shfl_xor(mxn, d));

    short8 qf[2][2];
    f32x4 cin[2];
    #pragma unroll
    for (int qt = 0; qt < 2; ++qt) {
        const int row = s0 + 32 * w + 16 * qt + l15;
        const unsigned short* qp = Tb + (size_t)row * DIM + quad * 8;
        qf[qt][0] = *(const short8*)(qp);
        qf[qt][1] = *(const short8*)(qp + 32);
        const float mrow = Norms[(size_t)b * SEQ + row] * mxn;
        cin[qt] = (f32x4){-mrow, -mrow, -mrow, -mrow};
    }

    f32x4 acc_o[2][4];
    #pragma unroll
    for (int qt = 0; qt < 2; ++qt)
        #pragma unroll
        for (int ct = 0; ct < 4; ++ct) acc_o[qt][ct] = (f32x4){0.f, 0.f, 0.f, 0.f};
    f32x4 lp4[2];
    lp4[0] = (f32x4){0.f, 0.f, 0.f, 0.f};
    lp4[1] = (f32x4){0.f, 0.f, 0.f, 0.f};

    // ---- loop-invariant addresses ----
    const int rsw  = l15 & 7;                       // K 3-bit key (128B rows)
    const int vkey = (l15 & 3) ^ (l15 >> 2);        // V/P 2-bit key (64B rows)
    const unsigned short* kb[2];
    #pragma unroll
    for (int ks = 0; ks < 2; ++ks)
        kb[ks] = sK + (l15 << 6) + (((quad + 4 * ks) ^ rsw) << 3);   // +HALF*2048 +mt*1024
    const unsigned short* vb = sV + (l15 << 5) + ((quad ^ vkey) << 3);  // +HALF*2048 +ct*512
    unsigned short* const prow = sP + (w << 10) + (l15 << 5);           // +qt*512
    unsigned short* pw[2];
    #pragma unroll
    for (int mt = 0; mt < 2; ++mt)
        pw[mt] = prow + ((((2 * mt + (quad >> 1)) ^ vkey) << 3) + ((quad & 1) << 2));
    const unsigned short* pr = prow + ((quad ^ vkey) << 3);

    // ---- staging (async global->LDS, 16B/lane) ----
    const int rl8 = lane >> 3, c8 = lane & 7;        // K: 8 rows x 8 chunks per call
    const int cgsK = c8 ^ rl8;
    const int rv = lane >> 2, cv = lane & 3;         // V: 16 rows x 4 chunks per call
    const int cvs = cv ^ ((rv & 3) ^ ((rv >> 2) & 3));
    const unsigned short* gK[2];
    const unsigned short* gV[2];
    #pragma unroll
    for (int j = 0; j < 2; ++j) {
        const int rowK = w * 16 + j * 8 + rl8;
        const int rowV = w * 32 + j * 16 + rv;
        gK[j] = Tb + (size_t)(kt0 * 32 + rowK) * 64 + cgsK * 8;
        gV[j] = Bb + (size_t)rowV * 4096 + kt0 * 32 + cvs * 8;
    }
    auto stageTo = [&](auto HC) {
        constexpr int HALF = decltype(HC)::value;
        #pragma unroll
        for (int j = 0; j < 2; ++j) {
            __builtin_amdgcn_global_load_lds(
                (const __attribute__((address_space(1))) unsigned int*)gK[j],
                (__attribute__((address_space(3))) unsigned int*)(sK + HALF * 2048 + (w * 16 + j * 8) * 64),
                16, 0, 0);
            __builtin_amdgcn_global_load_lds(
                (const __attribute__((address_space(1))) unsigned int*)gV[j],
                (__attribute__((address_space(3))) unsigned int*)(sV + HALF * 2048 + (w * 32 + j * 16) * 32),
                16, 0, 0);
        }
        #pragma unroll
        for (int j = 0; j < 2; ++j) { gK[j] += 2048; gV[j] += 32; }
    };

    auto computeT = [&](auto HC) {
        constexpr int HALF = decltype(HC)::value;
        short8 kf[2][2], vf[4];
        #pragma unroll
        for (int mt = 0; mt < 2; ++mt)
            #pragma unroll
            for (int ks = 0; ks < 2; ++ks)
                kf[ks][mt] = *(const short8*)(kb[ks] + HALF * 2048 + mt * 1024);
        #pragma unroll
        for (int ct = 0; ct < 4; ++ct)
            vf[ct] = *(const short8*)(vb + HALF * 2048 + ct * 512);

        // phase 1: all S-MFMAs (8)
        f32x4 a[2][2];
        #pragma unroll
        for (int qt = 0; qt < 2; ++qt)
            #pragma unroll
            for (int mt = 0; mt < 2; ++mt) {
                f32x4 s = cin[qt];
                s = __builtin_amdgcn_mfma_f32_16x16x32_bf16(kf[0][mt], qf[qt][0], s, 0, 0, 0);
                s = __builtin_amdgcn_mfma_f32_16x16x32_bf16(kf[1][mt], qf[qt][1], s, 0, 0, 0);
                a[qt][mt] = s;
            }
        // phase 2: exps + packs + lp partials; phase 3: P-writes
        #pragma unroll
        for (int qt = 0; qt < 2; ++qt)
            #pragma unroll
            for (int mt = 0; mt < 2; ++mt) {
                const float p0 = fast_exp2(a[qt][mt][0]);
                const float p1 = fast_exp2(a[qt][mt][1]);
                const float p2 = fast_exp2(a[qt][mt][2]);
                const float p3 = fast_exp2(a[qt][mt][3]);
                lp4[qt] += (f32x4){p0, p1, p2, p3};
                // truncating f32->bf16 pack (p in [0,1]; error << threshold)
                const unsigned lo = __builtin_amdgcn_perm(__float_as_uint(p1), __float_as_uint(p0), 0x07060302u);
                const unsigned hi = __builtin_amdgcn_perm(__float_as_uint(p3), __float_as_uint(p2), 0x07060302u);
                *(uint2*)(pw[mt] + qt * 512) = make_uint2(lo, hi);
            }
        // phase 4+5: P reads, then all PV-MFMAs (8)
        short8 pf[2];
        #pragma unroll
        for (int qt = 0; qt < 2; ++qt)
            pf[qt] = *(const short8*)(pr + qt * 512);
        #pragma unroll
        for (int qt = 0; qt < 2; ++qt)
            #pragma unroll
            for (int ct = 0; ct < 4; ++ct)
                acc_o[qt][ct] = __builtin_amdgcn_mfma_f32_16x16x32_bf16(pf[qt], vf[ct], acc_o[qt][ct], 0, 0, 0);
    };

    std::integral_constant<int, 0> H0;
    std::integral_constant<int, 1> H1;

    stageTo(H0);
    __syncthreads();
    for (int it = 0; it < niter; it += 2) {
        if (it + 1 < niter) stageTo(H1);
        computeT(H0);
        __syncthreads();
        if (it + 2 < niter) stageTo(H0);
        computeT(H1);
        __syncthreads();
    }

    float lp[2];
    #pragma unroll
    for (int qt = 0; qt < 2; ++qt) {
        lp[qt] = (lp4[qt][0] + lp4[qt][1]) + (lp4[qt][2] + lp4[qt][3]);
        lp[qt] += __shfl_xor(lp[qt], 16);
        lp[qt] += __shfl_xor(lp[qt], 32);
    }

    if (PARTIAL) {
        if (quad == 0) {
            #pragma unroll
            for (int qt = 0; qt < 2; ++qt)
                (Lbase + (size_t)h * 8 * SEQ)[(size_t)b * SEQ + s0 + 32 * w + 16 * qt + l15] = lp[qt];
        }
    } else {
        #pragma unroll
        for (int qt = 0; qt < 2; ++qt) {
            float inv[4];
            #pragma unroll
            for (int r = 0; r < 4; ++r) inv[r] = fast_rcp(__shfl(lp[qt], 4 * quad + r));
            #pragma unroll
            for (int ct = 0; ct < 4; ++ct)
                #pragma unroll
                for (int r = 0; r < 4; ++r) acc_o[qt][ct][r] *= inv[r];
        }
    }

    #pragma unroll
    for (int qt = 0; qt < 2; ++qt)
        #pragma unroll
        for (int ct = 0; ct < 4; ++ct) {
            const int c = 16 * ct + l15;
            #pragma unroll
            for (int r = 0; r < 4; ++r)
                sO[c * LDO + 32 * w + 16 * qt + 4 * quad + r] = acc_o[qt][ct][r];
        }
    __syncthreads();
    const int mw = tid & 15, cg = tid >> 4;
    if (PARTIAL) {
        unsigned short* Op = Obf + (size_t)h * 8 * DIM * SEQ;
        #pragma unroll
        for (int cc = 0; cc < 8; ++cc) {
            const int c = cg + 8 * cc;
            const f32x4 v = *(const f32x4*)(sO + c * LDO + 4 * mw);
            *(ushort4*)(Op + ((size_t)b * DIM + c) * SEQ + s0 + 4 * mw) =
                make_ushort4(f2bf(v.x), f2bf(v.y), f2bf(v.z), f2bf(v.w));
        }
    } else {
        #pragma unroll
        for (int cc = 0; cc < 8; ++cc) {
            const int c = cg + 8 * cc;
            const f32x4 v = *(const f32x4*)(sO + c * LDO + 4 * mw);
            *(f32x4*)(Out + ((size_t)b * DIM + c) * SEQ + s0 + 4 * mw) = v;
        }
    }
}

__global__ __launch_bounds__(256) void combine4(const unsigned short* __restrict__ Obf,
                                                const float* __restrict__ Lp,
                                                float* __restrict__ Out) {
    const int gid = blockIdx.x * 256 + threadIdx.x;
    const size_t base = (size_t)gid * 4;
    const int s = (int)(base & 4095);
    const int b = (int)(base >> 18);
    f32x4 os = (f32x4){0.f, 0.f, 0.f, 0.f};
    f32x4 ls = (f32x4){0.f, 0.f, 0.f, 0.f};
    #pragma unroll
    for (int h = 0; h < 4; ++h) {
        const ushort4 o = *(const ushort4*)(Obf + (size_t)h * 2097152 + base);
        os[0] += bf2f(o.x); os[1] += bf2f(o.y); os[2] += bf2f(o.z); os[3] += bf2f(o.w);
        const f32x4 l = *(const f32x4*)(Lp + (size_t)h * 8 * SEQ + b * SEQ + s);
        #pragma unroll
        for (int i = 0; i < 4; ++i) ls[i] += l[i];
    }
    f32x4 o;
    #pragma unroll
    for (int i = 0; i < 4; ++i) o[i] = os[i] / ls[i];
    *(f32x4*)(Out + base) = o;
}

__global__ __launch_bounds__(256, 2) void attn_fallback(const float* __restrict__ X,
                                                        float* __restrict__ Out) {
    __shared__ __align__(16) unsigned char smem[27648];
    unsigned short* sK = (unsigned short*)smem;
    unsigned short* sV = (unsigned short*)(smem + 9216);
    unsigned short* sP = (unsigned short*)(smem + 18432);
    float*          sO = (float*)smem;
    const int tid  = threadIdx.x;
    const int lane = tid & 63;
    const int w    = tid >> 6;
    const int l15  = lane & 15;
    const int quad = lane >> 4;
    const int b  = blockIdx.y;
    const int s0 = blockIdx.x * 64;
    const float* Xb = X + (size_t)b * DIM * SEQ;
    const int mgrp = tid & 15;
    const int c0   = tid >> 4;

    for (int cc = 0; cc < 4; ++cc) {
        int c = c0 + 16 * cc;
        const f32x4 v = *(const f32x4*)(Xb + (size_t)c * SEQ + s0 + 4 * mgrp);
        sK[(4 * mgrp + 0) * LDB + c] = f2bf(v.x);
        sK[(4 * mgrp + 1) * LDB + c] = f2bf(v.y);
        sK[(4 * mgrp + 2) * LDB + c] = f2bf(v.z);
        sK[(4 * mgrp + 3) * LDB + c] = f2bf(v.w);
    }
    __syncthreads();
    short8 qf0, qf1;
    {
        const int row = 16 * w + l15;
        qf0 = *(const short8*)(sK + row * LDB + quad * 8);
        qf1 = *(const short8*)(sK + row * LDB + 32 + quad * 8);
    }
    __syncthreads();
    f32x4 acc_o[4];
    for (int ct = 0; ct < 4; ++ct) acc_o[ct] = (f32x4){0.f, 0.f, 0.f, 0.f};
    float m_i[4] = {-1e30f, -1e30f, -1e30f, -1e30f};
    float l_i[4] = {0.f, 0.f, 0.f, 0.f};
    for (int kt = 0; kt < SEQ / 64; ++kt) {
        const int m0 = kt * 64;
        for (int cc = 0; cc < 4; ++cc) {
            int c = c0 + 16 * cc;
            const f32x4 v = *(const f32x4*)(Xb + (size_t)c * SEQ + m0 + 4 * mgrp);
            unsigned short h0 = f2bf(v.x), h1 = f2bf(v.y), h2 = f2bf(v.z), h3 = f2bf(v.w);
            *(ushort4*)(sV + c * LDB + 4 * mgrp) = make_ushort4(h0, h1, h2, h3);
            sK[(4 * mgrp + 0) * LDB + c] = h0;
            sK[(4 * mgrp + 1) * LDB + c] = h1;
            sK[(4 * mgrp + 2) * LDB + c] = h2;
            sK[(4 * mgrp + 3) * LDB + c] = h3;
        }
        __syncthreads();
        short8 vf[2][4];
        for (int ks = 0; ks < 2; ++ks)
            for (int ct = 0; ct < 4; ++ct)
                vf[ks][ct] = *(const short8*)(sV + (16 * ct + l15) * LDB + ks * 32 + quad * 8);
        f32x4 acc_s[4];
        for (int mt = 0; mt < 4; ++mt) {
            const int row = 16 * mt + l15;
            const short8 kf0 = *(const short8*)(sK + row * LDB + quad * 8);
            const short8 kf1 = *(const short8*)(sK + row * LDB + 32 + quad * 8);
            f32x4 a = (f32x4){0.f, 0.f, 0.f, 0.f};
            a = __builtin_amdgcn_mfma_f32_16x16x32_bf16(qf0, kf0, a, 0, 0, 0);
            a = __builtin_amdgcn_mfma_f32_16x16x32_bf16(qf1, kf1, a, 0, 0, 0);
            acc_s[mt] = a;
        }
        float alpha[4];
        for (int r = 0; r < 4; ++r) {
            float mx = fmaxf(fmaxf(acc_s[0][r], acc_s[1][r]), fmaxf(acc_s[2][r], acc_s[3][r]));
            mx = fmaxf(mx, __shfl_xor(mx, 1));
            mx = fmaxf(mx, __shfl_xor(mx, 2));
            mx = fmaxf(mx, __shfl_xor(mx, 4));
            mx = fmaxf(mx, __shfl_xor(mx, 8));
            const float mnew = fmaxf(m_i[r], mx);
            alpha[r] = __expf(m_i[r] - mnew);
            m_i[r] = mnew;
        }
        float rowsum[4] = {0.f, 0.f, 0.f, 0.f};
        unsigned short pb[4][4];
        for (int mt = 0; mt < 4; ++mt)
            for (int r = 0; r < 4; ++r) {
                const float p = __expf(acc_s[mt][r] - m_i[r]);
                rowsum[r] += p;
                pb[mt][r] = f2bf(p);
            }
        for (int r = 0; r < 4; ++r) {
            float s = rowsum[r];
            s += __shfl_xor(s, 1);
            s += __shfl_xor(s, 2);
            s += __shfl_xor(s, 4);
            s += __shfl_xor(s, 8);
            l_i[r] = alpha[r] * l_i[r] + s;
        }
        for (int ct = 0; ct < 4; ++ct)
            for (int r = 0; r < 4; ++r)
                acc_o[ct][r] *= alpha[r];
        for (int mt = 0; mt < 4; ++mt)
            for (int r = 0; r < 4; ++r)
                sP[(16 * w + quad * 4 + r) * LDB + l15 + 16 * mt] = pb[mt][r];
        __syncthreads();
        const short8 pf0 = *(const short8*)(sP + (16 * w + l15) * LDB + quad * 8);
        const short8 pf1 = *(const short8*)(sP + (16 * w + l15) * LDB + 32 + quad * 8);
        for (int ct = 0; ct < 4; ++ct) {
            acc_o[ct] = __builtin_amdgcn_mfma_f32_16x16x32_bf16(pf0, vf[0][ct], acc_o[ct], 0, 0, 0);
            acc_o[ct] = __builtin_amdgcn_mfma_f32_16x16x32_bf16(pf1, vf[1][ct], acc_o[ct], 0, 0, 0);
        }
    }
    float inv[4];
    for (int r = 0; r < 4; ++r) inv[r] = 1.f / l_i[r];
    for (int ct = 0; ct < 4; ++ct) {
        const int c = 16 * ct + l15;
        for (int r = 0; r < 4; ++r)
            sO[c * LDO + 16 * w + quad * 4 + r] = acc_o[ct][r] * inv[r];
    }
    __syncthreads();
    for (int cc = 0; cc < 4; ++cc) {
        const int c = c0 + 16 * cc;
        const f32x4 v = *(const f32x4*)(sO + c * LDO + 4 * mgrp);
        *(f32x4*)(Out + (size_t)b * DIM * SEQ + (size_t)c * SEQ + s0 + 4 * mgrp) = v;
    }
}

extern "C" void kernel_launch(void* const* d_in, const int* in_sizes, int n_in,
                              void* d_out, int out_size, void* d_ws, size_t ws_size,
                              hipStream_t stream) {
    const float* X = (const float*)d_in[0];
    float* Out = (float*)d_out;
    const size_t elems = (size_t)8 * SEQ * DIM;               // 2M
    const size_t offXbfT  = elems * 2;                        // Xbf 4MB
    const size_t offNorms = offXbfT + elems * 2;              // 8MB
    const size_t offMaxP  = offNorms + (size_t)8 * SEQ * 4;   // +128KB
    const size_t offObf   = offMaxP + 8 * 64 * 4;             // +2KB
    const size_t offLpart = offObf + 4 * elems * 2;           // +16MB (4 bf16 slabs)
    const size_t need_split = offLpart + 4 * (size_t)8 * SEQ * 4;  // ~24.64MB
    const size_t need_h1    = offObf;

    if (ws_size >= need_h1) {
        unsigned short* Xbf   = (unsigned short*)d_ws;
        unsigned short* XbfT  = (unsigned short*)((char*)d_ws + offXbfT);
        float* Norms   = (float*)((char*)d_ws + offNorms);
        float* MaxPart = (float*)((char*)d_ws + offMaxP);
        prepass3<<<dim3(64, 8), 256, 0, stream>>>(X, Xbf, XbfT, Norms, MaxPart);
        if (ws_size >= need_split) {
            unsigned short* Obf = (unsigned short*)((char*)d_ws + offObf);
            float* Lp = (float*)((char*)d_ws + offLpart);
            attn_split4<true><<<dim3(64, 8, 4), 128, 0, stream>>>(Xbf, XbfT, Norms, MaxPart,
                                                                  Obf, Lp, nullptr, 32);
            combine4<<<(int)(elems / 1024), 256, 0, stream>>>(Obf, Lp, Out);
        } else {
            attn_split4<false><<<dim3(64, 8, 1), 128, 0, stream>>>(Xbf, XbfT, Norms, MaxPart,
                                                                   nullptr, nullptr, Out, 128);
        }
    } else {
        attn_fallback<<<dim3(64, 8), 256, 0, stream>>>(X, Out);
    }
}